// Round 8
// baseline (678.923 us; speedup 1.0000x reference)
//
#include <hip/hip_runtime.h>

typedef unsigned short ushort_t;
typedef unsigned int uint_t;

#define N_NODES 100000
#define N_EDGES 1600000
#define N_PAIRS 1000000
#define SCAN_CHUNK 1024
#define NB_SCAN ((N_NODES + SCAN_CHUNK - 1) / SCAN_CHUNK)  // 98
#define BSHIFT 9
#define BUCKET (1 << BSHIFT)                               // 512-node buckets
#define NBUCKET ((N_NODES + BUCKET - 1) >> BSHIFT)         // 196
#define SC_T 512
#define SC_K 8
#define EPB (SC_T * SC_K)                                  // 4096 edges/block

// float4 component by (static) index — folds under full unroll.
#define COMP(v, k) ((k) == 0 ? (v).x : (k) == 1 ? (v).y : (k) == 2 ? (v).z : (v).w)

// ---- bf16 helpers (RNE) ----------------------------------------------------
__device__ __forceinline__ float bf2f(ushort_t u) {
    return __uint_as_float(((unsigned)u) << 16);
}
__device__ __forceinline__ ushort_t f2bf(float f) {
    unsigned u = __float_as_uint(f);
    return (ushort_t)((u + 0x7FFFu + ((u >> 16) & 1u)) >> 16);
}
// Unpack a 64B bf16 row (32 values) into f32 registers via 4 uint4 loads.
__device__ __forceinline__ void load_bf16_row(const ushort_t* __restrict__ p, float* X) {
    const uint4* rp = (const uint4*)p;
#pragma unroll
    for (int k = 0; k < 4; k++) {
        uint4 r = rp[k];
        uint_t u;
        u = r.x; X[8 * k + 0] = __uint_as_float(u << 16); X[8 * k + 1] = __uint_as_float(u & 0xFFFF0000u);
        u = r.y; X[8 * k + 2] = __uint_as_float(u << 16); X[8 * k + 3] = __uint_as_float(u & 0xFFFF0000u);
        u = r.z; X[8 * k + 4] = __uint_as_float(u << 16); X[8 * k + 5] = __uint_as_float(u & 0xFFFF0000u);
        u = r.w; X[8 * k + 6] = __uint_as_float(u << 16); X[8 * k + 7] = __uint_as_float(u & 0xFFFF0000u);
    }
}

// ---------------------------------------------------------------------------
// Convert f32 feature table -> bf16 table.
// ---------------------------------------------------------------------------
__global__ void cvt_kernel(const float* __restrict__ in, ushort_t* __restrict__ out) {
    int i = blockIdx.x * blockDim.x + threadIdx.x;  // over N*32/4
    if (i < N_NODES * 8) {
        float4 v = ((const float4*)in)[i];
        ushort4 o;
        o.x = f2bf(v.x); o.y = f2bf(v.y); o.z = f2bf(v.z); o.w = f2bf(v.w);
        ((ushort4*)out)[i] = o;
    }
}

// ---------------------------------------------------------------------------
// CSR build step 1: in-degree histogram (int atomics).
// ---------------------------------------------------------------------------
__global__ void degree_kernel(const int* __restrict__ dst, int* __restrict__ deg) {
    int e = blockIdx.x * blockDim.x + threadIdx.x;
    if (e < N_EDGES) atomicAdd(&deg[dst[e]], 1);
}

// ---------------------------------------------------------------------------
// CSR build step 2a: per-block inclusive scan of deg (1024 elems/block).
// ---------------------------------------------------------------------------
__global__ void scan1_kernel(const int* __restrict__ deg,
                             int* __restrict__ incl,
                             int* __restrict__ bsum) {
    __shared__ int part[256];
    int t = threadIdx.x;
    int idx = blockIdx.x * SCAN_CHUNK + t * 4;
    int4 v = make_int4(0, 0, 0, 0);
    if (idx + 3 < N_NODES) {
        v = *(const int4*)(deg + idx);
    } else {
        if (idx + 0 < N_NODES) v.x = deg[idx + 0];
        if (idx + 1 < N_NODES) v.y = deg[idx + 1];
        if (idx + 2 < N_NODES) v.z = deg[idx + 2];
        if (idx + 3 < N_NODES) v.w = deg[idx + 3];
    }
    int s0 = v.x, s1 = s0 + v.y, s2 = s1 + v.z, s3 = s2 + v.w;
    part[t] = s3;
    __syncthreads();
    for (int off = 1; off < 256; off <<= 1) {
        int val = (t >= off) ? part[t - off] : 0;
        __syncthreads();
        part[t] += val;
        __syncthreads();
    }
    int excl = (t > 0) ? part[t - 1] : 0;
    if (idx + 0 < N_NODES) incl[idx + 0] = excl + s0;
    if (idx + 1 < N_NODES) incl[idx + 1] = excl + s1;
    if (idx + 2 < N_NODES) incl[idx + 2] = excl + s2;
    if (idx + 3 < N_NODES) incl[idx + 3] = excl + s3;
    if (t == 255) bsum[blockIdx.x] = part[255];
}

// ---------------------------------------------------------------------------
// CSR build step 2b: exclusive scan of the 98 block sums (serial, tiny).
// ---------------------------------------------------------------------------
__global__ void scan2_kernel(int* __restrict__ bsum, int* __restrict__ offsets) {
    if (threadIdx.x == 0 && blockIdx.x == 0) {
        int run = 0;
        for (int i = 0; i < NB_SCAN; i++) {
            int t = bsum[i];
            bsum[i] = run;
            run += t;
        }
        offsets[N_NODES] = run;  // == N_EDGES
    }
}

// ---------------------------------------------------------------------------
// CSR build step 2c: finalize exclusive offsets; seed per-bucket cursors.
// ---------------------------------------------------------------------------
__global__ void scan3_kernel(const int* __restrict__ incl,
                             const int* __restrict__ deg,
                             const int* __restrict__ bsum,
                             int* __restrict__ offsets,
                             int* __restrict__ bcursor) {
    int i = blockIdx.x * blockDim.x + threadIdx.x;
    if (i < N_NODES) {
        int off = incl[i] - deg[i] + bsum[i / SCAN_CHUNK];
        offsets[i] = off;
        if ((i & (BUCKET - 1)) == 0) bcursor[i >> BSHIFT] = off;
    }
}

// ---------------------------------------------------------------------------
// CSR build 3a: bucket multisplit, packed 4B entries (src<<9 | dst_local).
// ---------------------------------------------------------------------------
__global__ void bscatter_kernel(const int* __restrict__ src,
                                const int* __restrict__ dst,
                                int* __restrict__ bcursor,
                                int* __restrict__ bed) {
    __shared__ int hist[NBUCKET];
    __shared__ int base[NBUCKET];
    __shared__ int stage[EPB];            // 16 KB
    __shared__ unsigned char sbkt[EPB];   // 4 KB
    int t = threadIdx.x;
    long long e0 = (long long)blockIdx.x * EPB;
    int cnt = (int)((N_EDGES - e0 < EPB) ? (N_EDGES - e0) : EPB);

    for (int i = t; i < NBUCKET; i += SC_T) hist[i] = 0;
    __syncthreads();
    for (int i = t; i < cnt; i += SC_T) {
        int s = src[e0 + i];
        int d = dst[e0 + i];
        int b = d >> BSHIFT;
        stage[i] = (s << BSHIFT) | (d & (BUCKET - 1));
        sbkt[i] = (unsigned char)b;  // NBUCKET=196 <= 255
        atomicAdd(&hist[b], 1);
    }
    __syncthreads();
    for (int i = t; i < NBUCKET; i += SC_T) {
        int c = hist[i];
        base[i] = c ? atomicAdd(&bcursor[i], c) : 0;
        hist[i] = 0;  // reuse as rank counter
    }
    __syncthreads();
    for (int i = t; i < cnt; i += SC_T) {
        int b = sbkt[i];
        int r = atomicAdd(&hist[b], 1);
        bed[base[b] + r] = stage[i];
    }
}

// ---------------------------------------------------------------------------
// CSR build 3b: fine scatter per bucket, 1024 threads/block (196 blocks ->
// 2x waves/bucket vs 512). Writes confined to the bucket's ~32KB region.
// ---------------------------------------------------------------------------
__global__ void ffill_kernel(const int* __restrict__ bed,
                             const int* __restrict__ offs,
                             int* __restrict__ csr) {
    __shared__ int cur[BUCKET];
    int b = blockIdx.x;
    int nbase = b << BSHIFT;
    int t = threadIdx.x;
    for (int i = t; i < BUCKET; i += blockDim.x) {
        int n = nbase + i;
        cur[i] = (n < N_NODES) ? offs[n] : 0;
    }
    __syncthreads();
    int nend = nbase + BUCKET;
    if (nend > N_NODES) nend = N_NODES;
    int beg = offs[nbase];
    int end = offs[nend];
    for (int i = beg + t; i < end; i += blockDim.x) {
        int p = bed[i];
        int pos = atomicAdd(&cur[p & (BUCKET - 1)], 1);
        csr[pos] = p >> BSHIFT;
    }
}

// ---------------------------------------------------------------------------
// Pure gather + mean (no LDS, no epilogue, low VGPR -> max occupancy).
// lane=channel, 8 nodes/block, 8-way unrolled coalesced 64B row gathers.
// Output: bf16 mean-agg rows (64B per group, coalesced).
// ---------------------------------------------------------------------------
__global__ void gather_kernel(const ushort_t* __restrict__ feat16,
                              const int* __restrict__ csr,
                              const int* __restrict__ offs,
                              ushort_t* __restrict__ agg16) {
    int g = threadIdx.x >> 5;
    int c = threadIdx.x & 31;
    int n = blockIdx.x * 8 + g;
    if (n >= N_NODES) return;

    const ushort_t* fc = feat16 + c;
    int beg = offs[n], end = offs[n + 1];
    float a0 = 0.f, a1 = 0.f, a2 = 0.f, a3 = 0.f;
    float a4 = 0.f, a5 = 0.f, a6 = 0.f, a7 = 0.f;
    int j = beg;
    for (; j + 7 < end; j += 8) {
        int s0 = csr[j + 0], s1 = csr[j + 1], s2 = csr[j + 2], s3 = csr[j + 3];
        int s4 = csr[j + 4], s5 = csr[j + 5], s6 = csr[j + 6], s7 = csr[j + 7];
        a0 += bf2f(fc[s0 * 32]); a1 += bf2f(fc[s1 * 32]);
        a2 += bf2f(fc[s2 * 32]); a3 += bf2f(fc[s3 * 32]);
        a4 += bf2f(fc[s4 * 32]); a5 += bf2f(fc[s5 * 32]);
        a6 += bf2f(fc[s6 * 32]); a7 += bf2f(fc[s7 * 32]);
    }
    for (; j < end; j++) a0 += bf2f(fc[csr[j] * 32]);
    float inv = 1.0f / (float)max(end - beg, 1);
    float acc = (((a0 + a1) + (a2 + a3)) + ((a4 + a5) + (a6 + a7))) * inv;
    agg16[(long long)n * 32 + c] = f2bf(acc);
}

// ---------------------------------------------------------------------------
// Linear: one THREAD per node. out[n,:] = act(agg[n,:]@Wl + b + root[n,:]@Wr).
// Weights in LDS, all reads wave-uniform broadcasts (conflict-free).
// 2048 FMAs fully unrolled, all register indices static. bf16 output via
// uint_t pk[16] (FIXED: was uint4 pk[2] overflow in round 7).
// ---------------------------------------------------------------------------
template <bool RELU, bool ROOT16>
__global__ void linear_kernel(const ushort_t* __restrict__ agg16,
                              const ushort_t* __restrict__ root16,
                              const float* __restrict__ root32,
                              const float* __restrict__ Wl,
                              const float* __restrict__ Wr,
                              const float* __restrict__ b,
                              ushort_t* __restrict__ out16) {
    __shared__ float4 sWl[256], sWr[256], sbv[8];
    int t = threadIdx.x;
    if (t < 256) {
        sWl[t] = ((const float4*)Wl)[t];
        sWr[t] = ((const float4*)Wr)[t];
    }
    if (t < 8) sbv[t] = ((const float4*)b)[t];
    __syncthreads();

    int n = blockIdx.x * blockDim.x + t;
    if (n >= N_NODES) return;

    float A[32];
    load_bf16_row(agg16 + (long long)n * 32, A);

    float X[32];
    if (ROOT16) {
        load_bf16_row(root16 + (long long)n * 32, X);
    } else {
        const float4* rp = (const float4*)(root32 + (long long)n * 32);
#pragma unroll
        for (int q = 0; q < 8; q++) {
            float4 v = rp[q];
            X[4 * q + 0] = v.x; X[4 * q + 1] = v.y; X[4 * q + 2] = v.z; X[4 * q + 3] = v.w;
        }
    }

    float4 O[8];
#pragma unroll
    for (int q = 0; q < 8; q++) O[q] = sbv[q];

#pragma unroll
    for (int i = 0; i < 32; i++) {
        float ai = A[i];
        float xi = X[i];
        const float4* wl = &sWl[i * 8];
        const float4* wr = &sWr[i * 8];
#pragma unroll
        for (int q = 0; q < 8; q++) {
            float4 wlv = wl[q];
            float4 wrv = wr[q];
            O[q].x += ai * wlv.x + xi * wrv.x;
            O[q].y += ai * wlv.y + xi * wrv.y;
            O[q].z += ai * wlv.z + xi * wrv.z;
            O[q].w += ai * wlv.w + xi * wrv.w;
        }
    }

    uint_t pk[16];
#pragma unroll
    for (int q = 0; q < 8; q++) {
        float4 v = O[q];
        if (RELU) {
            v.x = fmaxf(v.x, 0.f); v.y = fmaxf(v.y, 0.f);
            v.z = fmaxf(v.z, 0.f); v.w = fmaxf(v.w, 0.f);
        }
        pk[2 * q + 0] = (uint_t)f2bf(v.x) | ((uint_t)f2bf(v.y) << 16);
        pk[2 * q + 1] = (uint_t)f2bf(v.z) | ((uint_t)f2bf(v.w) << 16);
    }
    uint4* op = (uint4*)(out16 + (long long)n * 32);
    op[0] = make_uint4(pk[0], pk[1], pk[2], pk[3]);
    op[1] = make_uint4(pk[4], pk[5], pk[6], pk[7]);
    op[2] = make_uint4(pk[8], pk[9], pk[10], pk[11]);
    op[3] = make_uint4(pk[12], pk[13], pk[14], pk[15]);
}

// ---------------------------------------------------------------------------
// Pair scoring from bf16 z: 4 pairs per 8-lane group, ushort4 per lane.
// ---------------------------------------------------------------------------
__global__ void pair_kernel(const ushort_t* __restrict__ z16,
                            const int* __restrict__ pairs,
                            float* __restrict__ out) {
    int gid = blockIdx.x * blockDim.x + threadIdx.x;
    int q = gid >> 3;
    int l = gid & 7;
    if (q >= N_PAIRS / 4) return;
    const int4* pp = (const int4*)pairs;
    int4 i01 = pp[2 * q];
    int4 i23 = pp[2 * q + 1];
    const ushort_t* zl = z16 + l * 4;
    ushort4 a0 = *(const ushort4*)(zl + (long long)i01.x * 32);
    ushort4 b0 = *(const ushort4*)(zl + (long long)i01.y * 32);
    ushort4 a1 = *(const ushort4*)(zl + (long long)i01.z * 32);
    ushort4 b1 = *(const ushort4*)(zl + (long long)i01.w * 32);
    ushort4 a2 = *(const ushort4*)(zl + (long long)i23.x * 32);
    ushort4 b2 = *(const ushort4*)(zl + (long long)i23.y * 32);
    ushort4 a3 = *(const ushort4*)(zl + (long long)i23.z * 32);
    ushort4 b3 = *(const ushort4*)(zl + (long long)i23.w * 32);
    float d0 = bf2f(a0.x) * bf2f(b0.x) + bf2f(a0.y) * bf2f(b0.y)
             + bf2f(a0.z) * bf2f(b0.z) + bf2f(a0.w) * bf2f(b0.w);
    float d1 = bf2f(a1.x) * bf2f(b1.x) + bf2f(a1.y) * bf2f(b1.y)
             + bf2f(a1.z) * bf2f(b1.z) + bf2f(a1.w) * bf2f(b1.w);
    float d2 = bf2f(a2.x) * bf2f(b2.x) + bf2f(a2.y) * bf2f(b2.y)
             + bf2f(a2.z) * bf2f(b2.z) + bf2f(a2.w) * bf2f(b2.w);
    float d3 = bf2f(a3.x) * bf2f(b3.x) + bf2f(a3.y) * bf2f(b3.y)
             + bf2f(a3.z) * bf2f(b3.z) + bf2f(a3.w) * bf2f(b3.w);
#pragma unroll
    for (int off = 4; off >= 1; off >>= 1) {
        d0 += __shfl_xor(d0, off, 8);
        d1 += __shfl_xor(d1, off, 8);
        d2 += __shfl_xor(d2, off, 8);
        d3 += __shfl_xor(d3, off, 8);
    }
    if (l < 4) {
        float v = (l == 0) ? d0 : (l == 1) ? d1 : (l == 2) ? d2 : d3;
        out[4 * q + l] = v;
    }
}

// ---------------------------------------------------------------------------
extern "C" void kernel_launch(void* const* d_in, const int* in_sizes, int n_in,
                              void* d_out, int out_size, void* d_ws, size_t ws_size,
                              hipStream_t stream) {
    const float* x   = (const float*)d_in[0];
    const int*   ei  = (const int*)d_in[1];   // [2, E] row-major
    const int*   prs = (const int*)d_in[2];   // [P, 2] row-major
    const float* Wl1 = (const float*)d_in[3];
    const float* Wr1 = (const float*)d_in[4];
    const float* b1  = (const float*)d_in[5];
    const float* Wl2 = (const float*)d_in[6];
    const float* Wr2 = (const float*)d_in[7];
    const float* b2  = (const float*)d_in[8];
    float* out = (float*)d_out;

    const int* src = ei;
    const int* dst = ei + N_EDGES;

    // ws (~33.2 MB): x16 6.4 | h16 6.4 | z16 6.4 | csr 6.4 | agg16 6.4 | misc 1.2
    // bed (E ints, 6.4MB) aliases z16: fully consumed by ffill before linear2
    // writes z16 (fixed stream order, safe under graph replay).
    ushort_t* x16   = (ushort_t*)d_ws;
    ushort_t* h16   = x16 + (size_t)N_NODES * 32;
    ushort_t* z16   = h16 + (size_t)N_NODES * 32;
    int* csr        = (int*)(z16 + (size_t)N_NODES * 32);
    ushort_t* agg16 = (ushort_t*)(csr + N_EDGES);
    int* deg        = (int*)(agg16 + (size_t)N_NODES * 32);
    int* incl       = deg + N_NODES;
    int* offsets    = incl + N_NODES;
    int* bsum       = offsets + (N_NODES + 1);
    int* bcursor    = bsum + 128;
    int* bed        = (int*)z16;

    const int BT = 256;
    int cvt_blocks  = (N_NODES * 8 + BT - 1) / BT;
    int edge_blocks = (N_EDGES + BT - 1) / BT;
    int node_blocks = (N_NODES + BT - 1) / BT;
    int bsc_blocks  = (N_EDGES + EPB - 1) / EPB;   // 391
    int gat_blocks  = (N_NODES + 7) / 8;           // 12500
    int lin_blocks  = (N_NODES + BT - 1) / BT;     // 391
    int pair_blocks = (int)(((long long)N_PAIRS * 2 + BT - 1) / BT);

    // ---- CSR build + bf16 staging of x ----
    hipMemsetAsync(deg, 0, sizeof(int) * N_NODES, stream);
    cvt_kernel<<<cvt_blocks, BT, 0, stream>>>(x, x16);
    degree_kernel<<<edge_blocks, BT, 0, stream>>>(dst, deg);
    scan1_kernel<<<NB_SCAN, BT, 0, stream>>>(deg, incl, bsum);
    scan2_kernel<<<1, 64, 0, stream>>>(bsum, offsets);
    scan3_kernel<<<node_blocks, BT, 0, stream>>>(incl, deg, bsum, offsets, bcursor);
    bscatter_kernel<<<bsc_blocks, SC_T, 0, stream>>>(src, dst, bcursor, bed);
    ffill_kernel<<<NBUCKET, 1024, 0, stream>>>(bed, offsets, csr);

    // ---- layer 1: gather(x16) -> agg16; linear(agg16, x) -> h16 ----
    gather_kernel<<<gat_blocks, BT, 0, stream>>>(x16, csr, offsets, agg16);
    linear_kernel<true, false><<<lin_blocks, BT, 0, stream>>>(
        agg16, nullptr, x, Wl1, Wr1, b1, h16);

    // ---- layer 2: gather(h16) -> agg16; linear(agg16, h16) -> z16 ----
    gather_kernel<<<gat_blocks, BT, 0, stream>>>(h16, csr, offsets, agg16);
    linear_kernel<false, true><<<lin_blocks, BT, 0, stream>>>(
        agg16, h16, nullptr, Wl2, Wr2, b2, z16);

    // ---- pair scoring from bf16 z ----
    pair_kernel<<<pair_blocks, BT, 0, stream>>>(z16, prs, out);
}

// Round 9
// 309.678 us; speedup vs baseline: 2.1924x; 2.1924x over previous
//
#include <hip/hip_runtime.h>

typedef unsigned short ushort_t;
typedef unsigned int uint_t;

#define N_NODES 100000
#define N_EDGES 1600000
#define N_PAIRS 1000000
#define BSHIFT 9
#define BUCKET (1 << BSHIFT)                               // 512-node buckets
#define NBUCKET ((N_NODES + BUCKET - 1) >> BSHIFT)         // 196
#define SC_T 512
#define SC_K 8
#define EPB (SC_T * SC_K)                                  // 4096 edges/block

// ---- bf16 helpers (RNE) ----------------------------------------------------
__device__ __forceinline__ float bf2f(ushort_t u) {
    return __uint_as_float(((unsigned)u) << 16);
}
__device__ __forceinline__ ushort_t f2bf(float f) {
    unsigned u = __float_as_uint(f);
    return (ushort_t)((u + 0x7FFFu + ((u >> 16) & 1u)) >> 16);
}

// ---------------------------------------------------------------------------
// Convert f32 feature table -> bf16 table.
// ---------------------------------------------------------------------------
__global__ void cvt_kernel(const float* __restrict__ in, ushort_t* __restrict__ out) {
    int i = blockIdx.x * blockDim.x + threadIdx.x;  // over N*32/4
    if (i < N_NODES * 8) {
        float4 v = ((const float4*)in)[i];
        ushort4 o;
        o.x = f2bf(v.x); o.y = f2bf(v.y); o.z = f2bf(v.z); o.w = f2bf(v.w);
        ((ushort4*)out)[i] = o;
    }
}

// ---------------------------------------------------------------------------
// Bucket-level histogram (196 bins) — replaces the per-node degree kernel.
// ---------------------------------------------------------------------------
__global__ void bhist_kernel(const int* __restrict__ dst, int* __restrict__ ghist) {
    __shared__ int hist[NBUCKET];
    int t = threadIdx.x;
    for (int i = t; i < NBUCKET; i += blockDim.x) hist[i] = 0;
    __syncthreads();
    long long e0 = (long long)blockIdx.x * EPB;
    long long e1 = e0 + EPB;
    if (e1 > N_EDGES) e1 = N_EDGES;
    for (long long i = e0 + t; i < e1; i += blockDim.x)
        atomicAdd(&hist[dst[i] >> BSHIFT], 1);
    __syncthreads();
    for (int i = t; i < NBUCKET; i += blockDim.x)
        if (hist[i]) atomicAdd(&ghist[i], hist[i]);
}

// ---------------------------------------------------------------------------
// Exclusive scan of the 196 bucket counts (1 block). Seeds bcursor and
// writes boff[NBUCKET] = offsets[N_NODES] = N_EDGES.
// ---------------------------------------------------------------------------
__global__ void bscan_kernel(const int* __restrict__ ghist, int* __restrict__ boff,
                             int* __restrict__ bcursor, int* __restrict__ offsets) {
    __shared__ int tmp[256];
    int t = threadIdx.x;
    tmp[t] = (t < NBUCKET) ? ghist[t] : 0;
    __syncthreads();
    for (int off = 1; off < 256; off <<= 1) {
        int v = (t >= off) ? tmp[t - off] : 0;
        __syncthreads();
        tmp[t] += v;
        __syncthreads();
    }
    int excl = (t > 0) ? tmp[t - 1] : 0;
    if (t < NBUCKET) { boff[t] = excl; bcursor[t] = excl; }
    if (t == NBUCKET) {
        boff[t] = excl;            // == N_EDGES
        offsets[N_NODES] = excl;   // gather's sentinel
    }
}

// ---------------------------------------------------------------------------
// Bucket multisplit, packed 4B entries (src<<9 | dst_local). LDS-staged;
// one global cursor atomic per (block,bucket); contiguous run writes.
// ---------------------------------------------------------------------------
__global__ void bscatter_kernel(const int* __restrict__ src,
                                const int* __restrict__ dst,
                                int* __restrict__ bcursor,
                                int* __restrict__ bed) {
    __shared__ int hist[NBUCKET];
    __shared__ int base[NBUCKET];
    __shared__ int stage[EPB];            // 16 KB
    __shared__ unsigned char sbkt[EPB];   // 4 KB
    int t = threadIdx.x;
    long long e0 = (long long)blockIdx.x * EPB;
    int cnt = (int)((N_EDGES - e0 < EPB) ? (N_EDGES - e0) : EPB);

    for (int i = t; i < NBUCKET; i += SC_T) hist[i] = 0;
    __syncthreads();
    for (int i = t; i < cnt; i += SC_T) {
        int s = src[e0 + i];
        int d = dst[e0 + i];
        int b = d >> BSHIFT;
        stage[i] = (s << BSHIFT) | (d & (BUCKET - 1));
        sbkt[i] = (unsigned char)b;  // NBUCKET=196 <= 255
        atomicAdd(&hist[b], 1);
    }
    __syncthreads();
    for (int i = t; i < NBUCKET; i += SC_T) {
        int c = hist[i];
        base[i] = c ? atomicAdd(&bcursor[i], c) : 0;
        hist[i] = 0;  // reuse as rank counter
    }
    __syncthreads();
    for (int i = t; i < cnt; i += SC_T) {
        int b = sbkt[i];
        int r = atomicAdd(&hist[b], 1);
        bed[base[b] + r] = stage[i];
    }
}

// ---------------------------------------------------------------------------
// Fine scatter per bucket + per-node offsets (fused; replaces the old
// 100k-node scan chain). One block per bucket, 1024 threads:
//   pass A: count per-node in LDS; in-LDS 512-wide exclusive scan;
//           write offsets[n] (coalesced).
//   pass B: place entries via LDS cursors; csr writes confined to the
//           bucket's contiguous ~32KB region.
// ---------------------------------------------------------------------------
__global__ void ffill_kernel(const int* __restrict__ bed,
                             const int* __restrict__ boff,
                             int* __restrict__ offsets,
                             int* __restrict__ csr) {
    __shared__ int cnt[BUCKET];
    __shared__ int scn[BUCKET];
    __shared__ int cur[BUCKET];
    int b = blockIdx.x;
    int t = threadIdx.x;  // 0..1023
    int base = boff[b], bend = boff[b + 1];

    if (t < BUCKET) cnt[t] = 0;
    __syncthreads();
    for (int i = base + t; i < bend; i += blockDim.x)
        atomicAdd(&cnt[bed[i] & (BUCKET - 1)], 1);
    __syncthreads();
    if (t < BUCKET) scn[t] = cnt[t];
    __syncthreads();
    for (int off = 1; off < BUCKET; off <<= 1) {
        int v = 0;
        if (t < BUCKET && t >= off) v = scn[t - off];
        __syncthreads();
        if (t < BUCKET) scn[t] += v;
        __syncthreads();
    }
    if (t < BUCKET) {
        int excl = scn[t] - cnt[t];
        cur[t] = base + excl;
        int n = (b << BSHIFT) + t;
        if (n < N_NODES) offsets[n] = base + excl;
    }
    __syncthreads();
    for (int i = base + t; i < bend; i += blockDim.x) {
        int p = bed[i];
        int pos = atomicAdd(&cur[p & (BUCKET - 1)], 1);
        csr[pos] = p >> BSHIFT;
    }
}

// ---------------------------------------------------------------------------
// Fused pull-aggregate + mean + dual matvec + bias (+ReLU), bf16 gathers.
// Proven round-6 structure: lane=channel, 8 nodes/block, 8-way unrolled
// coalesced 64B row gathers. ROOT16: root feature from bf16 table (layer 2)
// vs f32 input (layer 1). Output bf16.
// ---------------------------------------------------------------------------
template <bool RELU, bool ROOT16>
__global__ void agg_linear_kernel(const ushort_t* __restrict__ feat16,
                                  const float* __restrict__ feat32,
                                  const int* __restrict__ csr,
                                  const int* __restrict__ offs,
                                  const float* __restrict__ Wl,
                                  const float* __restrict__ Wr,
                                  const float* __restrict__ b,
                                  ushort_t* __restrict__ out16) {
    __shared__ float sWl[1024], sWr[1024], sb[32];
    for (int i = threadIdx.x; i < 1024; i += blockDim.x) {
        sWl[i] = Wl[i];
        sWr[i] = Wr[i];
    }
    if (threadIdx.x < 32) sb[threadIdx.x] = b[threadIdx.x];
    __syncthreads();

    int g = threadIdx.x >> 5;
    int c = threadIdx.x & 31;
    int n = blockIdx.x * 8 + g;
    if (n >= N_NODES) return;

    const ushort_t* fc = feat16 + c;
    int beg = offs[n], end = offs[n + 1];
    float a0 = 0.f, a1 = 0.f, a2 = 0.f, a3 = 0.f;
    float a4 = 0.f, a5 = 0.f, a6 = 0.f, a7 = 0.f;
    int j = beg;
    for (; j + 7 < end; j += 8) {
        int s0 = csr[j + 0], s1 = csr[j + 1], s2 = csr[j + 2], s3 = csr[j + 3];
        int s4 = csr[j + 4], s5 = csr[j + 5], s6 = csr[j + 6], s7 = csr[j + 7];
        a0 += bf2f(fc[s0 * 32]); a1 += bf2f(fc[s1 * 32]);
        a2 += bf2f(fc[s2 * 32]); a3 += bf2f(fc[s3 * 32]);
        a4 += bf2f(fc[s4 * 32]); a5 += bf2f(fc[s5 * 32]);
        a6 += bf2f(fc[s6 * 32]); a7 += bf2f(fc[s7 * 32]);
    }
    for (; j < end; j++) a0 += bf2f(fc[csr[j] * 32]);
    float inv = 1.0f / (float)max(end - beg, 1);
    float acc = (((a0 + a1) + (a2 + a3)) + ((a4 + a5) + (a6 + a7))) * inv;
    float xr = ROOT16 ? bf2f(fc[n * 32]) : feat32[(long long)n * 32 + c];

    float o = sb[c];
#pragma unroll
    for (int i = 0; i < 32; i++) {
        float ai = __shfl(acc, i, 32);
        float xi = __shfl(xr, i, 32);
        o += ai * sWl[i * 32 + c] + xi * sWr[i * 32 + c];
    }
    float r = RELU ? fmaxf(o, 0.f) : o;
    out16[(long long)n * 32 + c] = f2bf(r);
}

// ---------------------------------------------------------------------------
// Pair scoring from bf16 z: 4 consecutive pairs per 8-lane group; ushort4
// per lane per endpoint; 8 independent gathers in flight; contiguous 16B
// store per group.
// ---------------------------------------------------------------------------
__global__ void pair_kernel(const ushort_t* __restrict__ z16,
                            const int* __restrict__ pairs,
                            float* __restrict__ out) {
    int gid = blockIdx.x * blockDim.x + threadIdx.x;
    int q = gid >> 3;
    int l = gid & 7;
    if (q >= N_PAIRS / 4) return;
    const int4* pp = (const int4*)pairs;
    int4 i01 = pp[2 * q];
    int4 i23 = pp[2 * q + 1];
    const ushort_t* zl = z16 + l * 4;
    ushort4 a0 = *(const ushort4*)(zl + (long long)i01.x * 32);
    ushort4 b0 = *(const ushort4*)(zl + (long long)i01.y * 32);
    ushort4 a1 = *(const ushort4*)(zl + (long long)i01.z * 32);
    ushort4 b1 = *(const ushort4*)(zl + (long long)i01.w * 32);
    ushort4 a2 = *(const ushort4*)(zl + (long long)i23.x * 32);
    ushort4 b2 = *(const ushort4*)(zl + (long long)i23.y * 32);
    ushort4 a3 = *(const ushort4*)(zl + (long long)i23.z * 32);
    ushort4 b3 = *(const ushort4*)(zl + (long long)i23.w * 32);
    float d0 = bf2f(a0.x) * bf2f(b0.x) + bf2f(a0.y) * bf2f(b0.y)
             + bf2f(a0.z) * bf2f(b0.z) + bf2f(a0.w) * bf2f(b0.w);
    float d1 = bf2f(a1.x) * bf2f(b1.x) + bf2f(a1.y) * bf2f(b1.y)
             + bf2f(a1.z) * bf2f(b1.z) + bf2f(a1.w) * bf2f(b1.w);
    float d2 = bf2f(a2.x) * bf2f(b2.x) + bf2f(a2.y) * bf2f(b2.y)
             + bf2f(a2.z) * bf2f(b2.z) + bf2f(a2.w) * bf2f(b2.w);
    float d3 = bf2f(a3.x) * bf2f(b3.x) + bf2f(a3.y) * bf2f(b3.y)
             + bf2f(a3.z) * bf2f(b3.z) + bf2f(a3.w) * bf2f(b3.w);
#pragma unroll
    for (int off = 4; off >= 1; off >>= 1) {
        d0 += __shfl_xor(d0, off, 8);
        d1 += __shfl_xor(d1, off, 8);
        d2 += __shfl_xor(d2, off, 8);
        d3 += __shfl_xor(d3, off, 8);
    }
    if (l < 4) {
        float v = (l == 0) ? d0 : (l == 1) ? d1 : (l == 2) ? d2 : d3;
        out[4 * q + l] = v;
    }
}

// ---------------------------------------------------------------------------
extern "C" void kernel_launch(void* const* d_in, const int* in_sizes, int n_in,
                              void* d_out, int out_size, void* d_ws, size_t ws_size,
                              hipStream_t stream) {
    const float* x   = (const float*)d_in[0];
    const int*   ei  = (const int*)d_in[1];   // [2, E] row-major
    const int*   prs = (const int*)d_in[2];   // [P, 2] row-major
    const float* Wl1 = (const float*)d_in[3];
    const float* Wr1 = (const float*)d_in[4];
    const float* b1  = (const float*)d_in[5];
    const float* Wl2 = (const float*)d_in[6];
    const float* Wr2 = (const float*)d_in[7];
    const float* b2  = (const float*)d_in[8];
    float* out = (float*)d_out;

    const int* src = ei;
    const int* dst = ei + N_EDGES;

    // ws (~27 MB): x16 6.4 | h16 6.4 | z16 6.4 | csr 6.4 | offsets 0.4 | misc
    // bed (E ints, 6.4MB) aliases z16: fully consumed by ffill before layer 2
    // writes z16 (fixed stream order, safe under graph replay).
    ushort_t* x16 = (ushort_t*)d_ws;
    ushort_t* h16 = x16 + (size_t)N_NODES * 32;
    ushort_t* z16 = h16 + (size_t)N_NODES * 32;
    int* csr      = (int*)(z16 + (size_t)N_NODES * 32);
    int* offsets  = csr + N_EDGES;            // N+1
    int* ghist    = offsets + (N_NODES + 1);  // 196
    int* boff     = ghist + NBUCKET;          // 197
    int* bcursor  = boff + (NBUCKET + 1);     // 196
    int* bed      = (int*)z16;

    const int BT = 256;
    int cvt_blocks  = (N_NODES * 8 + BT - 1) / BT;        // 3125
    int bsc_blocks  = (N_EDGES + EPB - 1) / EPB;          // 391
    int agg_blocks  = (N_NODES + 7) / 8;                  // 12500
    int pair_blocks = (int)(((long long)N_PAIRS * 2 + BT - 1) / BT);

    // ---- bucket-sorted CSR build + bf16 staging of x ----
    hipMemsetAsync(ghist, 0, sizeof(int) * NBUCKET, stream);
    cvt_kernel<<<cvt_blocks, BT, 0, stream>>>(x, x16);
    bhist_kernel<<<bsc_blocks, BT, 0, stream>>>(dst, ghist);
    bscan_kernel<<<1, 256, 0, stream>>>(ghist, boff, bcursor, offsets);
    bscatter_kernel<<<bsc_blocks, SC_T, 0, stream>>>(src, dst, bcursor, bed);
    ffill_kernel<<<NBUCKET, 1024, 0, stream>>>(bed, boff, offsets, csr);

    // ---- layer 1: x16 -> h16 (root from f32 x) ----
    agg_linear_kernel<true, false><<<agg_blocks, BT, 0, stream>>>(
        x16, x, csr, offsets, Wl1, Wr1, b1, h16);
    // ---- layer 2: h16 -> z16 (root from h16; z16 overwrites dead bed) ----
    agg_linear_kernel<false, true><<<agg_blocks, BT, 0, stream>>>(
        h16, nullptr, csr, offsets, Wl2, Wr2, b2, z16);

    // ---- pair scoring from bf16 z ----
    pair_kernel<<<pair_blocks, BT, 0, stream>>>(z16, prs, out);
}

// Round 10
// 303.041 us; speedup vs baseline: 2.2404x; 1.0219x over previous
//
#include <hip/hip_runtime.h>

typedef unsigned short ushort_t;
typedef unsigned int uint_t;

#define N_NODES 100000
#define N_EDGES 1600000
#define N_PAIRS 1000000
#define BSHIFT 9
#define BUCKET (1 << BSHIFT)                               // 512-node buckets
#define NBUCKET ((N_NODES + BUCKET - 1) >> BSHIFT)         // 196
#define SC_T 512
#define SC_K 8
#define EPB (SC_T * SC_K)                                  // 4096 edges/block

// ---- bf16 helpers (RNE) ----------------------------------------------------
__device__ __forceinline__ float bf2f(ushort_t u) {
    return __uint_as_float(((unsigned)u) << 16);
}
__device__ __forceinline__ ushort_t f2bf(float f) {
    unsigned u = __float_as_uint(f);
    return (ushort_t)((u + 0x7FFFu + ((u >> 16) & 1u)) >> 16);
}
__device__ __forceinline__ uint_t pk2(float a, float b) {
    return (uint_t)f2bf(a) | ((uint_t)f2bf(b) << 16);
}
// Unpack 16 bf16 (32B) into 16 floats via 2 uint4 loads.
__device__ __forceinline__ void load_bf16_half(const ushort_t* __restrict__ p, float* X) {
    const uint4* rp = (const uint4*)p;
#pragma unroll
    for (int k = 0; k < 2; k++) {
        uint4 r = rp[k];
        uint_t u;
        u = r.x; X[8 * k + 0] = __uint_as_float(u << 16); X[8 * k + 1] = __uint_as_float(u & 0xFFFF0000u);
        u = r.y; X[8 * k + 2] = __uint_as_float(u << 16); X[8 * k + 3] = __uint_as_float(u & 0xFFFF0000u);
        u = r.z; X[8 * k + 4] = __uint_as_float(u << 16); X[8 * k + 5] = __uint_as_float(u & 0xFFFF0000u);
        u = r.w; X[8 * k + 6] = __uint_as_float(u << 16); X[8 * k + 7] = __uint_as_float(u & 0xFFFF0000u);
    }
}

// ---------------------------------------------------------------------------
// Convert f32 features -> TWO bf16 half-tables [N][16] (3.2MB each, so each
// fits a 4MB per-XCD L2 during the gather).
// ---------------------------------------------------------------------------
__global__ void cvt_kernel(const float* __restrict__ in,
                           ushort_t* __restrict__ outA,
                           ushort_t* __restrict__ outB) {
    int t = blockIdx.x * blockDim.x + threadIdx.x;  // over 2N
    if (t >= 2 * N_NODES) return;
    int n = t >> 1, h = t & 1;
    const float4* p = (const float4*)(in + (long long)n * 32 + h * 16);
    float4 v0 = p[0], v1 = p[1], v2 = p[2], v3 = p[3];
    uint4 o0 = make_uint4(pk2(v0.x, v0.y), pk2(v0.z, v0.w), pk2(v1.x, v1.y), pk2(v1.z, v1.w));
    uint4 o1 = make_uint4(pk2(v2.x, v2.y), pk2(v2.z, v2.w), pk2(v3.x, v3.y), pk2(v3.z, v3.w));
    uint4* o = (uint4*)((h ? outB : outA) + (long long)n * 16);
    o[0] = o0;
    o[1] = o1;
}

// ---------------------------------------------------------------------------
// Bucket-level histogram (196 bins).
// ---------------------------------------------------------------------------
__global__ void bhist_kernel(const int* __restrict__ dst, int* __restrict__ ghist) {
    __shared__ int hist[NBUCKET];
    int t = threadIdx.x;
    for (int i = t; i < NBUCKET; i += blockDim.x) hist[i] = 0;
    __syncthreads();
    long long e0 = (long long)blockIdx.x * EPB;
    long long e1 = e0 + EPB;
    if (e1 > N_EDGES) e1 = N_EDGES;
    for (long long i = e0 + t; i < e1; i += blockDim.x)
        atomicAdd(&hist[dst[i] >> BSHIFT], 1);
    __syncthreads();
    for (int i = t; i < NBUCKET; i += blockDim.x)
        if (hist[i]) atomicAdd(&ghist[i], hist[i]);
}

// ---------------------------------------------------------------------------
// Exclusive scan of bucket counts; seeds bcursor; offsets[N] sentinel.
// ---------------------------------------------------------------------------
__global__ void bscan_kernel(const int* __restrict__ ghist, int* __restrict__ boff,
                             int* __restrict__ bcursor, int* __restrict__ offsets) {
    __shared__ int tmp[256];
    int t = threadIdx.x;
    tmp[t] = (t < NBUCKET) ? ghist[t] : 0;
    __syncthreads();
    for (int off = 1; off < 256; off <<= 1) {
        int v = (t >= off) ? tmp[t - off] : 0;
        __syncthreads();
        tmp[t] += v;
        __syncthreads();
    }
    int excl = (t > 0) ? tmp[t - 1] : 0;
    if (t < NBUCKET) { boff[t] = excl; bcursor[t] = excl; }
    if (t == NBUCKET) {
        boff[t] = excl;
        offsets[N_NODES] = excl;  // == N_EDGES
    }
}

// ---------------------------------------------------------------------------
// Bucket multisplit, packed 4B entries (src<<9 | dst_local).
// ---------------------------------------------------------------------------
__global__ void bscatter_kernel(const int* __restrict__ src,
                                const int* __restrict__ dst,
                                int* __restrict__ bcursor,
                                int* __restrict__ bed) {
    __shared__ int hist[NBUCKET];
    __shared__ int base[NBUCKET];
    __shared__ int stage[EPB];            // 16 KB
    __shared__ unsigned char sbkt[EPB];   // 4 KB
    int t = threadIdx.x;
    long long e0 = (long long)blockIdx.x * EPB;
    int cnt = (int)((N_EDGES - e0 < EPB) ? (N_EDGES - e0) : EPB);

    for (int i = t; i < NBUCKET; i += SC_T) hist[i] = 0;
    __syncthreads();
    for (int i = t; i < cnt; i += SC_T) {
        int s = src[e0 + i];
        int d = dst[e0 + i];
        int b = d >> BSHIFT;
        stage[i] = (s << BSHIFT) | (d & (BUCKET - 1));
        sbkt[i] = (unsigned char)b;  // NBUCKET=196 <= 255
        atomicAdd(&hist[b], 1);
    }
    __syncthreads();
    for (int i = t; i < NBUCKET; i += SC_T) {
        int c = hist[i];
        base[i] = c ? atomicAdd(&bcursor[i], c) : 0;
        hist[i] = 0;  // reuse as rank counter
    }
    __syncthreads();
    for (int i = t; i < cnt; i += SC_T) {
        int b = sbkt[i];
        int r = atomicAdd(&hist[b], 1);
        bed[base[b] + r] = stage[i];
    }
}

// ---------------------------------------------------------------------------
// Fine scatter per bucket + per-node offsets (fused), 1024 threads/block.
// ---------------------------------------------------------------------------
__global__ void ffill_kernel(const int* __restrict__ bed,
                             const int* __restrict__ boff,
                             int* __restrict__ offsets,
                             int* __restrict__ csr) {
    __shared__ int cnt[BUCKET];
    __shared__ int scn[BUCKET];
    __shared__ int cur[BUCKET];
    int b = blockIdx.x;
    int t = threadIdx.x;  // 0..1023
    int base = boff[b], bend = boff[b + 1];

    if (t < BUCKET) cnt[t] = 0;
    __syncthreads();
    for (int i = base + t; i < bend; i += blockDim.x)
        atomicAdd(&cnt[bed[i] & (BUCKET - 1)], 1);
    __syncthreads();
    if (t < BUCKET) scn[t] = cnt[t];
    __syncthreads();
    for (int off = 1; off < BUCKET; off <<= 1) {
        int v = 0;
        if (t < BUCKET && t >= off) v = scn[t - off];
        __syncthreads();
        if (t < BUCKET) scn[t] += v;
        __syncthreads();
    }
    if (t < BUCKET) {
        int excl = scn[t] - cnt[t];
        cur[t] = base + excl;
        int n = (b << BSHIFT) + t;
        if (n < N_NODES) offsets[n] = base + excl;
    }
    __syncthreads();
    for (int i = base + t; i < bend; i += blockDim.x) {
        int p = bed[i];
        int pos = atomicAdd(&cur[p & (BUCKET - 1)], 1);
        csr[pos] = p >> BSHIFT;
    }
}

// ---------------------------------------------------------------------------
// Half-table gather + mean: 16 lanes per node (lane=channel), 32B rows from
// a 3.2MB table (fits per-XCD L2). No LDS, no epilogue -> low VGPR, high
// occupancy, pure row-request pipeline. 16 nodes/block.
// ---------------------------------------------------------------------------
__global__ void gather16_kernel(const ushort_t* __restrict__ featH,
                                const int* __restrict__ csr,
                                const int* __restrict__ offs,
                                ushort_t* __restrict__ aggH) {
    int g = threadIdx.x >> 4;   // group 0..15
    int c = threadIdx.x & 15;   // channel 0..15
    int n = blockIdx.x * 16 + g;
    if (n >= N_NODES) return;

    const ushort_t* fc = featH + c;
    int beg = offs[n], end = offs[n + 1];
    float a0 = 0.f, a1 = 0.f, a2 = 0.f, a3 = 0.f;
    float a4 = 0.f, a5 = 0.f, a6 = 0.f, a7 = 0.f;
    int j = beg;
    for (; j + 7 < end; j += 8) {
        int s0 = csr[j + 0], s1 = csr[j + 1], s2 = csr[j + 2], s3 = csr[j + 3];
        int s4 = csr[j + 4], s5 = csr[j + 5], s6 = csr[j + 6], s7 = csr[j + 7];
        a0 += bf2f(fc[s0 * 16]); a1 += bf2f(fc[s1 * 16]);
        a2 += bf2f(fc[s2 * 16]); a3 += bf2f(fc[s3 * 16]);
        a4 += bf2f(fc[s4 * 16]); a5 += bf2f(fc[s5 * 16]);
        a6 += bf2f(fc[s6 * 16]); a7 += bf2f(fc[s7 * 16]);
    }
    for (; j < end; j++) a0 += bf2f(fc[csr[j] * 16]);
    float inv = 1.0f / (float)max(end - beg, 1);
    float acc = (((a0 + a1) + (a2 + a3)) + ((a4 + a5) + (a6 + a7))) * inv;
    aggH[(long long)n * 16 + c] = f2bf(acc);
}

// ---------------------------------------------------------------------------
// Linear: one THREAD per node, __launch_bounds__(256,1) so the register
// allocator may use up to ~512 VGPRs (round-8 spill was a 64-VGPR cap ->
// 636MB scratch traffic). All indices static under full unroll.
// out halves written separately so the next gather reads 3.2MB tables.
// ---------------------------------------------------------------------------
template <bool RELU, bool ROOT16>
__global__ __launch_bounds__(256, 1) void linear_kernel(
    const ushort_t* __restrict__ aggA, const ushort_t* __restrict__ aggB,
    const ushort_t* __restrict__ rootA, const ushort_t* __restrict__ rootB,
    const float* __restrict__ root32,
    const float* __restrict__ Wl, const float* __restrict__ Wr,
    const float* __restrict__ b,
    ushort_t* __restrict__ outA, ushort_t* __restrict__ outB) {
    __shared__ float4 sWl[256], sWr[256], sbv[8];
    int t = threadIdx.x;
    if (t < 256) {
        sWl[t] = ((const float4*)Wl)[t];
        sWr[t] = ((const float4*)Wr)[t];
    }
    if (t < 8) sbv[t] = ((const float4*)b)[t];
    __syncthreads();

    int n = blockIdx.x * blockDim.x + t;
    if (n >= N_NODES) return;

    float A[32];
    load_bf16_half(aggA + (long long)n * 16, A);
    load_bf16_half(aggB + (long long)n * 16, A + 16);

    float X[32];
    if (ROOT16) {
        load_bf16_half(rootA + (long long)n * 16, X);
        load_bf16_half(rootB + (long long)n * 16, X + 16);
    } else {
        const float4* rp = (const float4*)(root32 + (long long)n * 32);
#pragma unroll
        for (int q = 0; q < 8; q++) {
            float4 v = rp[q];
            X[4 * q + 0] = v.x; X[4 * q + 1] = v.y; X[4 * q + 2] = v.z; X[4 * q + 3] = v.w;
        }
    }

    float4 O[8];
#pragma unroll
    for (int q = 0; q < 8; q++) O[q] = sbv[q];

#pragma unroll
    for (int i = 0; i < 32; i++) {
        float ai = A[i];
        float xi = X[i];
        const float4* wl = &sWl[i * 8];
        const float4* wr = &sWr[i * 8];
#pragma unroll
        for (int q = 0; q < 8; q++) {
            float4 wlv = wl[q];
            float4 wrv = wr[q];
            O[q].x += ai * wlv.x + xi * wrv.x;
            O[q].y += ai * wlv.y + xi * wrv.y;
            O[q].z += ai * wlv.z + xi * wrv.z;
            O[q].w += ai * wlv.w + xi * wrv.w;
        }
    }

    uint_t pk[16];
#pragma unroll
    for (int q = 0; q < 8; q++) {
        float4 v = O[q];
        if (RELU) {
            v.x = fmaxf(v.x, 0.f); v.y = fmaxf(v.y, 0.f);
            v.z = fmaxf(v.z, 0.f); v.w = fmaxf(v.w, 0.f);
        }
        pk[2 * q + 0] = pk2(v.x, v.y);
        pk[2 * q + 1] = pk2(v.z, v.w);
    }
    uint4* oa = (uint4*)(outA + (long long)n * 16);
    oa[0] = make_uint4(pk[0], pk[1], pk[2], pk[3]);
    oa[1] = make_uint4(pk[4], pk[5], pk[6], pk[7]);
    uint4* ob = (uint4*)(outB + (long long)n * 16);
    ob[0] = make_uint4(pk[8], pk[9], pk[10], pk[11]);
    ob[1] = make_uint4(pk[12], pk[13], pk[14], pk[15]);
}

// ---------------------------------------------------------------------------
// Pair scoring, one half-table per pass (3.2MB, L2-resident). 4 pairs per
// 8-lane group; each lane reads ushort2 (4B) of each endpoint's 32B half-row.
// Pass A writes out, pass B accumulates.
// ---------------------------------------------------------------------------
template <bool ADD>
__global__ void pair_kernel(const ushort_t* __restrict__ zH,
                            const int* __restrict__ pairs,
                            float* __restrict__ out) {
    int gid = blockIdx.x * blockDim.x + threadIdx.x;
    int q = gid >> 3;
    int l = gid & 7;
    if (q >= N_PAIRS / 4) return;
    const int4* pp = (const int4*)pairs;
    int4 i01 = pp[2 * q];
    int4 i23 = pp[2 * q + 1];
    const ushort_t* zl = zH + l * 2;
    ushort2 a0 = *(const ushort2*)(zl + (long long)i01.x * 16);
    ushort2 b0 = *(const ushort2*)(zl + (long long)i01.y * 16);
    ushort2 a1 = *(const ushort2*)(zl + (long long)i01.z * 16);
    ushort2 b1 = *(const ushort2*)(zl + (long long)i01.w * 16);
    ushort2 a2 = *(const ushort2*)(zl + (long long)i23.x * 16);
    ushort2 b2 = *(const ushort2*)(zl + (long long)i23.y * 16);
    ushort2 a3 = *(const ushort2*)(zl + (long long)i23.z * 16);
    ushort2 b3 = *(const ushort2*)(zl + (long long)i23.w * 16);
    float d0 = bf2f(a0.x) * bf2f(b0.x) + bf2f(a0.y) * bf2f(b0.y);
    float d1 = bf2f(a1.x) * bf2f(b1.x) + bf2f(a1.y) * bf2f(b1.y);
    float d2 = bf2f(a2.x) * bf2f(b2.x) + bf2f(a2.y) * bf2f(b2.y);
    float d3 = bf2f(a3.x) * bf2f(b3.x) + bf2f(a3.y) * bf2f(b3.y);
#pragma unroll
    for (int off = 4; off >= 1; off >>= 1) {
        d0 += __shfl_xor(d0, off, 8);
        d1 += __shfl_xor(d1, off, 8);
        d2 += __shfl_xor(d2, off, 8);
        d3 += __shfl_xor(d3, off, 8);
    }
    if (l < 4) {
        float v = (l == 0) ? d0 : (l == 1) ? d1 : (l == 2) ? d2 : d3;
        int idx = 4 * q + l;
        out[idx] = ADD ? (out[idx] + v) : v;
    }
}

// ---------------------------------------------------------------------------
extern "C" void kernel_launch(void* const* d_in, const int* in_sizes, int n_in,
                              void* d_out, int out_size, void* d_ws, size_t ws_size,
                              hipStream_t stream) {
    const float* x   = (const float*)d_in[0];
    const int*   ei  = (const int*)d_in[1];   // [2, E] row-major
    const int*   prs = (const int*)d_in[2];   // [P, 2] row-major
    const float* Wl1 = (const float*)d_in[3];
    const float* Wr1 = (const float*)d_in[4];
    const float* b1  = (const float*)d_in[5];
    const float* Wl2 = (const float*)d_in[6];
    const float* Wr2 = (const float*)d_in[7];
    const float* b2  = (const float*)d_in[8];
    float* out = (float*)d_out;

    const int* src = ei;
    const int* dst = ei + N_EDGES;

    // ws (~32.4 MB): xA xB hA hB aggA aggB (6 x 3.2MB) | csr 6.4 | zA zB 6.4
    //                | offsets/ghist/boff/bcursor ~0.4
    // bed (E ints = 6.4MB) aliases zA+zB: fully consumed by ffill before
    // linear2 writes z (fixed stream order, safe under graph replay).
    ushort_t* xA   = (ushort_t*)d_ws;
    ushort_t* xB   = xA + (size_t)N_NODES * 16;
    ushort_t* hA   = xB + (size_t)N_NODES * 16;
    ushort_t* hB   = hA + (size_t)N_NODES * 16;
    ushort_t* aggA = hB + (size_t)N_NODES * 16;
    ushort_t* aggB = aggA + (size_t)N_NODES * 16;
    int* csr       = (int*)(aggB + (size_t)N_NODES * 16);
    ushort_t* zA   = (ushort_t*)(csr + N_EDGES);
    ushort_t* zB   = zA + (size_t)N_NODES * 16;
    int* offsets   = (int*)(zB + (size_t)N_NODES * 16);  // N+1
    int* ghist     = offsets + (N_NODES + 1);            // 196
    int* boff      = ghist + NBUCKET;                    // 197
    int* bcursor   = boff + (NBUCKET + 1);               // 196
    int* bed       = (int*)zA;                           // E ints == zA+zB

    const int BT = 256;
    int cvt_blocks  = (2 * N_NODES + BT - 1) / BT;        // 782
    int bsc_blocks  = (N_EDGES + EPB - 1) / EPB;          // 391
    int g16_blocks  = (N_NODES + 15) / 16;                // 6250
    int lin_blocks  = (N_NODES + BT - 1) / BT;            // 391
    int pair_blocks = (int)(((long long)N_PAIRS * 2 + BT - 1) / BT);

    // ---- CSR build + split bf16 staging of x ----
    hipMemsetAsync(ghist, 0, sizeof(int) * NBUCKET, stream);
    cvt_kernel<<<cvt_blocks, BT, 0, stream>>>(x, xA, xB);
    bhist_kernel<<<bsc_blocks, BT, 0, stream>>>(dst, ghist);
    bscan_kernel<<<1, 256, 0, stream>>>(ghist, boff, bcursor, offsets);
    bscatter_kernel<<<bsc_blocks, SC_T, 0, stream>>>(src, dst, bcursor, bed);
    ffill_kernel<<<NBUCKET, 1024, 0, stream>>>(bed, boff, offsets, csr);

    // ---- layer 1: gather halves of x; linear -> hA,hB ----
    gather16_kernel<<<g16_blocks, BT, 0, stream>>>(xA, csr, offsets, aggA);
    gather16_kernel<<<g16_blocks, BT, 0, stream>>>(xB, csr, offsets, aggB);
    linear_kernel<true, false><<<lin_blocks, BT, 0, stream>>>(
        aggA, aggB, nullptr, nullptr, x, Wl1, Wr1, b1, hA, hB);

    // ---- layer 2: gather halves of h; linear -> zA,zB (overwrites dead bed) ----
    gather16_kernel<<<g16_blocks, BT, 0, stream>>>(hA, csr, offsets, aggA);
    gather16_kernel<<<g16_blocks, BT, 0, stream>>>(hB, csr, offsets, aggB);
    linear_kernel<false, true><<<lin_blocks, BT, 0, stream>>>(
        aggA, aggB, hA, hB, nullptr, Wl2, Wr2, b2, zA, zB);

    // ---- pair scoring: two L2-resident half passes ----
    pair_kernel<false><<<pair_blocks, BT, 0, stream>>>(zA, prs, out);
    pair_kernel<true><<<pair_blocks, BT, 0, stream>>>(zB, prs, out);
}